// Round 1
// baseline (256.162 us; speedup 1.0000x reference)
//
#include <hip/hip_runtime.h>
#include <hip/hip_bf16.h>

#define B_N  128
#define VIS  4096
#define HID  4096
#define EMB  512
#define NNEG 2048

using f32x4  = __attribute__((ext_vector_type(4))) float;
using bf16x8 = __attribute__((ext_vector_type(8))) short;

static __device__ __forceinline__ unsigned short f2bf(float f) {
  unsigned u = __builtin_bit_cast(unsigned, f);
  u += 0x7fffu + ((u >> 16) & 1u);   // RNE
  return (unsigned short)(u >> 16);
}

union U16x8 { unsigned short us[8]; uint4 v; };
union U16x4 { unsigned short us[4]; uint2 v; };

// GEMM1: P[split][128][4096] partial of vfs @ W_h^T (+ b_h in split 0)
// grid (128 n-tiles, 4 k-splits), block 256. BM=128, BN=32, K-chunk=1024, BK=64.
__global__ __launch_bounds__(256) void gemm1_kernel(
    const float* __restrict__ vfs, const float* __restrict__ Wh,
    const float* __restrict__ bh, float* __restrict__ P) {
  const int n0    = blockIdx.x * 32;
  const int split = blockIdx.y;
  const int kbase = split * 1024;

  __shared__ __align__(16) unsigned short As[128 * 64];
  __shared__ __align__(16) unsigned short Ws[32 * 64];

  const int t = threadIdx.x;
  const int w = t >> 6;
  const int lane = t & 63;
  const int m_lane = lane & 15;
  const int kq = lane >> 4;

  f32x4 acc[2][2] = {};

  const int ar = t >> 1;
  const int ac = (t & 1) * 32;
  const int wr = t >> 3;
  const int wc = (t & 7) * 8;
  const float* Ag = vfs + ar * VIS + kbase + ac;
  const float* Wg = Wh + (size_t)(n0 + wr) * VIS + kbase + wc;

  for (int kt = 0; kt < 16; ++kt) {
    float4 av[8];
#pragma unroll
    for (int i = 0; i < 8; ++i) av[i] = ((const float4*)Ag)[i];
    float4 wv0 = ((const float4*)Wg)[0];
    float4 wv1 = ((const float4*)Wg)[1];
    Ag += 64; Wg += 64;

    __syncthreads();   // previous iter's LDS reads done
#pragma unroll
    for (int i = 0; i < 4; ++i) {
      U16x8 pk;
      const float4 x = av[2 * i], y = av[2 * i + 1];
      pk.us[0] = f2bf(x.x); pk.us[1] = f2bf(x.y); pk.us[2] = f2bf(x.z); pk.us[3] = f2bf(x.w);
      pk.us[4] = f2bf(y.x); pk.us[5] = f2bf(y.y); pk.us[6] = f2bf(y.z); pk.us[7] = f2bf(y.w);
      const int G = (t & 1) * 4 + i;                       // 16B k-group
      *(uint4*)&As[ar * 64 + ((G ^ (ar & 7)) * 8)] = pk.v; // XOR swizzle
    }
    {
      U16x8 pk;
      pk.us[0] = f2bf(wv0.x); pk.us[1] = f2bf(wv0.y); pk.us[2] = f2bf(wv0.z); pk.us[3] = f2bf(wv0.w);
      pk.us[4] = f2bf(wv1.x); pk.us[5] = f2bf(wv1.y); pk.us[6] = f2bf(wv1.z); pk.us[7] = f2bf(wv1.w);
      const int G = t & 7;
      *(uint4*)&Ws[wr * 64 + ((G ^ (wr & 7)) * 8)] = pk.v;
    }
    __syncthreads();

#pragma unroll
    for (int ks = 0; ks < 2; ++ks) {
      const int Gk = ks * 4 + kq;
      const int m0 = w * 32 + m_lane;
      const int m1 = m0 + 16;
      bf16x8 a0 = *(const bf16x8*)&As[m0 * 64 + ((Gk ^ (m0 & 7)) * 8)];
      bf16x8 a1 = *(const bf16x8*)&As[m1 * 64 + ((Gk ^ (m1 & 7)) * 8)];
      const int nA = m_lane, nB = m_lane + 16;
      bf16x8 b0 = *(const bf16x8*)&Ws[nA * 64 + ((Gk ^ (nA & 7)) * 8)];
      bf16x8 b1 = *(const bf16x8*)&Ws[nB * 64 + ((Gk ^ (nB & 7)) * 8)];
      acc[0][0] = __builtin_amdgcn_mfma_f32_16x16x32_bf16(a0, b0, acc[0][0], 0, 0, 0);
      acc[0][1] = __builtin_amdgcn_mfma_f32_16x16x32_bf16(a0, b1, acc[0][1], 0, 0, 0);
      acc[1][0] = __builtin_amdgcn_mfma_f32_16x16x32_bf16(a1, b0, acc[1][0], 0, 0, 0);
      acc[1][1] = __builtin_amdgcn_mfma_f32_16x16x32_bf16(a1, b1, acc[1][1], 0, 0, 0);
    }
  }

  // epilogue: C/D layout col=lane&15, row=(lane>>4)*4+r
  float* Pd = P + (size_t)split * (B_N * HID);
  const int rq = (lane >> 4) * 4;
#pragma unroll
  for (int mi = 0; mi < 2; ++mi) {
#pragma unroll
    for (int ni = 0; ni < 2; ++ni) {
      const int ng = n0 + ni * 16 + m_lane;
      const float bias = (split == 0) ? bh[ng] : 0.0f;
#pragma unroll
      for (int r = 0; r < 4; ++r) {
        const int mg = w * 32 + mi * 16 + rq + r;
        Pd[mg * HID + ng] = acc[mi][ni][r] + bias;
      }
    }
  }
}

// GEMM2: emb[128,512] += (sum_p P_p) @ W_e^T (+ b_e once). grid (32 n-tiles, 8 k-splits).
// BM=128, BN=16, K-chunk=512, BK=64. fp32 atomicAdd into zeroed emb.
__global__ __launch_bounds__(256) void gemm2_kernel(
    const float* __restrict__ P, const float* __restrict__ We,
    const float* __restrict__ be, float* __restrict__ emb) {
  const int n0    = blockIdx.x * 16;
  const int split = blockIdx.y;
  const int kbase = split * 512;

  __shared__ __align__(16) unsigned short As[128 * 64];
  __shared__ __align__(16) unsigned short Ws[16 * 64];

  const int t = threadIdx.x, w = t >> 6, lane = t & 63;
  const int m_lane = lane & 15, kq = lane >> 4;
  f32x4 acc[2] = {};

  const int ar = t >> 1, ac = (t & 1) * 32;
  const int wr = t >> 4, wc = (t & 15) * 4;
  const float* A0 = P + ar * HID + kbase + ac;
  const float* A1 = A0 + (size_t)B_N * HID;
  const float* A2 = A1 + (size_t)B_N * HID;
  const float* A3 = A2 + (size_t)B_N * HID;
  const float* Wg = We + (size_t)(n0 + wr) * HID + kbase + wc;

  for (int kt = 0; kt < 8; ++kt) {
    float4 av[8];
#pragma unroll
    for (int i = 0; i < 8; ++i) {
      float4 s0 = ((const float4*)A0)[i];
      float4 s1 = ((const float4*)A1)[i];
      float4 s2 = ((const float4*)A2)[i];
      float4 s3 = ((const float4*)A3)[i];
      av[i] = make_float4(s0.x + s1.x + s2.x + s3.x, s0.y + s1.y + s2.y + s3.y,
                          s0.z + s1.z + s2.z + s3.z, s0.w + s1.w + s2.w + s3.w);
    }
    float4 wv = ((const float4*)Wg)[0];
    A0 += 64; A1 += 64; A2 += 64; A3 += 64; Wg += 64;

    __syncthreads();
#pragma unroll
    for (int i = 0; i < 4; ++i) {
      U16x8 pk;
      const float4 x = av[2 * i], y = av[2 * i + 1];
      pk.us[0] = f2bf(x.x); pk.us[1] = f2bf(x.y); pk.us[2] = f2bf(x.z); pk.us[3] = f2bf(x.w);
      pk.us[4] = f2bf(y.x); pk.us[5] = f2bf(y.y); pk.us[6] = f2bf(y.z); pk.us[7] = f2bf(y.w);
      const int G = (t & 1) * 4 + i;
      *(uint4*)&As[ar * 64 + ((G ^ (ar & 7)) * 8)] = pk.v;
    }
    {
      U16x4 pk;
      pk.us[0] = f2bf(wv.x); pk.us[1] = f2bf(wv.y); pk.us[2] = f2bf(wv.z); pk.us[3] = f2bf(wv.w);
      const int G = (t & 15) >> 1;
      *(uint2*)&Ws[wr * 64 + ((G ^ (wr & 7)) * 8) + (t & 1) * 4] = pk.v;
    }
    __syncthreads();

#pragma unroll
    for (int ks = 0; ks < 2; ++ks) {
      const int Gk = ks * 4 + kq;
      const int m0 = w * 32 + m_lane, m1 = m0 + 16;
      bf16x8 a0 = *(const bf16x8*)&As[m0 * 64 + ((Gk ^ (m0 & 7)) * 8)];
      bf16x8 a1 = *(const bf16x8*)&As[m1 * 64 + ((Gk ^ (m1 & 7)) * 8)];
      bf16x8 b0 = *(const bf16x8*)&Ws[m_lane * 64 + ((Gk ^ (m_lane & 7)) * 8)];
      acc[0] = __builtin_amdgcn_mfma_f32_16x16x32_bf16(a0, b0, acc[0], 0, 0, 0);
      acc[1] = __builtin_amdgcn_mfma_f32_16x16x32_bf16(a1, b0, acc[1], 0, 0, 0);
    }
  }

  const int rq = (lane >> 4) * 4;
  const int ng = n0 + m_lane;
  const float bias = (split == 0) ? be[ng] : 0.0f;
#pragma unroll
  for (int mi = 0; mi < 2; ++mi) {
#pragma unroll
    for (int r = 0; r < 4; ++r) {
      const int mg = w * 32 + mi * 16 + rq + r;
      atomicAdd(&emb[mg * EMB + ng], acc[mi][r] + bias);
    }
  }
}

// Scores. Blocks 0..255: 8 negatives x all 128 b. Blocks 256..263: positives.
__global__ __launch_bounds__(256) void score_kernel(
    const float* __restrict__ emb, const float* __restrict__ n_lfs,
    const float* __restrict__ p_lfs, float* __restrict__ out) {
  const int bid = blockIdx.x;
  const int t = threadIdx.x;
  if (bid < NNEG / 8) {
    __shared__ __align__(16) float nl[8 * EMB];
    const int n0 = bid * 8;
#pragma unroll
    for (int i = 0; i < 4; ++i)
      ((float4*)nl)[t + i * 256] = ((const float4*)(n_lfs + (size_t)n0 * EMB))[t + i * 256];
    __syncthreads();
    const int nloc = t >> 5;           // which of 8 negatives
    const int l = t & 31;              // 32 lanes share one (b,n) reduction
    const float* nrow = nl + nloc * EMB;
    for (int b = 0; b < B_N; ++b) {
      const float* eb = emb + b * EMB;
      float s = 0.f;
#pragma unroll
      for (int q = 0; q < 8; ++q) {
        const int d = q * 64 + l * 2;
        float2 nv = *(const float2*)(nrow + d);
        float2 ev = *(const float2*)(eb + d);
        float d0 = fmaxf(nv.x - ev.x, 0.f);
        float d1 = fmaxf(nv.y - ev.y, 0.f);
        s = fmaf(d0, d0, s);
        s = fmaf(d1, d1, s);
      }
#pragma unroll
      for (int off = 16; off > 0; off >>= 1) s += __shfl_xor(s, off, 64);
      if (l == 0) out[(size_t)b * (NNEG + 1) + 1 + n0 + nloc] = -sqrtf(s);
    }
  } else {
    const int j = bid - NNEG / 8;      // 0..7, 16 b each, one wave per 4 b
    const int w = t >> 6, lane = t & 63;
#pragma unroll
    for (int i = 0; i < 4; ++i) {
      const int b = j * 16 + w * 4 + i;
      const float* eb = emb + b * EMB;
      const float* pb = p_lfs + b * EMB;
      float s = 0.f;
#pragma unroll
      for (int q = 0; q < 4; ++q) {
        const int d = q * 128 + lane * 2;
        float2 pv = *(const float2*)(pb + d);
        float2 ev = *(const float2*)(eb + d);
        float d0 = fmaxf(pv.x - ev.x, 0.f);
        float d1 = fmaxf(pv.y - ev.y, 0.f);
        s = fmaf(d0, d0, s);
        s = fmaf(d1, d1, s);
      }
#pragma unroll
      for (int off = 32; off > 0; off >>= 1) s += __shfl_xor(s, off, 64);
      if (lane == 0) out[(size_t)b * (NNEG + 1)] = -sqrtf(s);
    }
  }
}

extern "C" void kernel_launch(void* const* d_in, const int* in_sizes, int n_in,
                              void* d_out, int out_size, void* d_ws, size_t ws_size,
                              hipStream_t stream) {
  const float* vfs   = (const float*)d_in[0];
  const float* p_lfs = (const float*)d_in[1];
  const float* n_lfs = (const float*)d_in[2];
  const float* W_h   = (const float*)d_in[3];
  const float* b_h   = (const float*)d_in[4];
  const float* W_e   = (const float*)d_in[5];
  const float* b_e   = (const float*)d_in[6];
  float* out = (float*)d_out;

  float* P   = (float*)d_ws;                       // 4 * 128 * 4096 fp32 = 8 MB
  float* emb = P + (size_t)4 * B_N * HID;          // 128 * 512 fp32

  hipMemsetAsync(emb, 0, (size_t)B_N * EMB * sizeof(float), stream);
  gemm1_kernel<<<dim3(HID / 32, 4), 256, 0, stream>>>(vfs, W_h, b_h, P);
  gemm2_kernel<<<dim3(EMB / 16, 8), 256, 0, stream>>>(P, W_e, b_e, emb);
  score_kernel<<<dim3(NNEG / 8 + 8), 256, 0, stream>>>(emb, n_lfs, p_lfs, out);
}

// Round 2
// 160.502 us; speedup vs baseline: 1.5960x; 1.5960x over previous
//
#include <hip/hip_runtime.h>

#define B_N  128
#define VIS  4096
#define HID  4096
#define EMB  512
#define NNEG 2048
#define OUTN (NNEG + 1)

using f32x4  = __attribute__((ext_vector_type(4))) float;
using bf16x8 = __attribute__((ext_vector_type(8))) short;

static __device__ __forceinline__ unsigned short f2bf(float f) {
  unsigned u = __builtin_bit_cast(unsigned, f);
  u += 0x7fffu + ((u >> 16) & 1u);   // RNE
  return (unsigned short)(u >> 16);
}

union U16x8 { unsigned short us[8]; uint4 v; };
union U16x4 { unsigned short us[4]; uint2 v; };

// async global->LDS, 16B per lane; LDS dest = uniform base + lane*16
static __device__ __forceinline__ void glds16(const void* g, void* l) {
  __builtin_amdgcn_global_load_lds(
      (const __attribute__((address_space(1))) unsigned*)g,
      (__attribute__((address_space(3))) unsigned*)l, 16, 0, 0);
}

// prep: vfs fp32 [128,4096] -> Abf bf16 bits
__global__ __launch_bounds__(256) void prep_kernel(
    const float* __restrict__ src, unsigned short* __restrict__ dst) {
  const int idx = blockIdx.x * 256 + threadIdx.x;   // 65536 threads, 8 elem each
  float4 a = ((const float4*)src)[idx * 2];
  float4 b = ((const float4*)src)[idx * 2 + 1];
  U16x8 pk;
  pk.us[0] = f2bf(a.x); pk.us[1] = f2bf(a.y); pk.us[2] = f2bf(a.z); pk.us[3] = f2bf(a.w);
  pk.us[4] = f2bf(b.x); pk.us[5] = f2bf(b.y); pk.us[6] = f2bf(b.z); pk.us[7] = f2bf(b.w);
  ((uint4*)dst)[idx] = pk.v;
}

// GEMM1: Hf[128,4096] += vfs(bf16) @ W_h^T (+ b_h in split 0), fp32 atomics.
// grid (128 n-tiles, 4 k-splits), 256 thr. BM=128 BN=32 BK=64, 16 K-steps.
__global__ __launch_bounds__(256, 2) void gemm1_kernel(
    const unsigned short* __restrict__ Abf, const float* __restrict__ Wh,
    const float* __restrict__ bh, float* __restrict__ Hf) {
  const int n0    = blockIdx.x * 32;
  const int kbase = blockIdx.y * 1024;

  __shared__ __align__(16) unsigned short As[128 * 64];
  __shared__ __align__(16) unsigned short Ws[32 * 64];

  const int t = threadIdx.x, w = t >> 6, lane = t & 63;
  const int m_lane = lane & 15, kq = lane >> 4;
  f32x4 acc[2][2] = {};

  // W staging map (fp32 -> cvt -> LDS): 8 elem/thread
  const int wr = t >> 3, wc = (t & 7) * 8, Gw = t & 7;
  const float* Wg = Wh + (size_t)(n0 + wr) * VIS + kbase + wc;
  float4 wv0 = ((const float4*)Wg)[0];
  float4 wv1 = ((const float4*)Wg)[1];
  Wg += 64;

  // A glds lane map: slot SL = i*256 + w*64 + lane -> row m=SL>>3, pos p=SL&7,
  // stored k-group G = p ^ (m&7)  (swizzle applied on the global address side)
  const int rowA = lane >> 3;
  const int gA   = (lane & 7) ^ rowA;

  for (int kt = 0; kt < 16; ++kt) {
    __syncthreads();   // previous iter's LDS reads complete
#pragma unroll
    for (int i = 0; i < 4; ++i) {
      const int m = i * 32 + w * 8 + rowA;
      const unsigned short* src = Abf + (size_t)m * VIS + kbase + kt * 64 + gA * 8;
      glds16(src, &As[(i * 256 + w * 64) * 8]);
    }
    {
      U16x8 pk;
      pk.us[0] = f2bf(wv0.x); pk.us[1] = f2bf(wv0.y); pk.us[2] = f2bf(wv0.z); pk.us[3] = f2bf(wv0.w);
      pk.us[4] = f2bf(wv1.x); pk.us[5] = f2bf(wv1.y); pk.us[6] = f2bf(wv1.z); pk.us[7] = f2bf(wv1.w);
      *(uint4*)&Ws[wr * 64 + ((Gw ^ (wr & 7)) * 8)] = pk.v;
    }
    if (kt < 15) {   // prefetch next W tile (guarded: last iter would read OOB)
      wv0 = ((const float4*)Wg)[0];
      wv1 = ((const float4*)Wg)[1];
      Wg += 64;
    }
    __syncthreads();  // drains glds (A tile ready)

#pragma unroll
    for (int ks = 0; ks < 2; ++ks) {
      const int Gk = ks * 4 + kq;
      const int m0 = w * 32 + m_lane, m1 = m0 + 16;
      bf16x8 a0 = *(const bf16x8*)&As[m0 * 64 + ((Gk ^ (m0 & 7)) * 8)];
      bf16x8 a1 = *(const bf16x8*)&As[m1 * 64 + ((Gk ^ (m1 & 7)) * 8)];
      const int nA = m_lane, nB = m_lane + 16;
      bf16x8 b0 = *(const bf16x8*)&Ws[nA * 64 + ((Gk ^ (nA & 7)) * 8)];
      bf16x8 b1 = *(const bf16x8*)&Ws[nB * 64 + ((Gk ^ (nB & 7)) * 8)];
      acc[0][0] = __builtin_amdgcn_mfma_f32_16x16x32_bf16(a0, b0, acc[0][0], 0, 0, 0);
      acc[0][1] = __builtin_amdgcn_mfma_f32_16x16x32_bf16(a0, b1, acc[0][1], 0, 0, 0);
      acc[1][0] = __builtin_amdgcn_mfma_f32_16x16x32_bf16(a1, b0, acc[1][0], 0, 0, 0);
      acc[1][1] = __builtin_amdgcn_mfma_f32_16x16x32_bf16(a1, b1, acc[1][1], 0, 0, 0);
    }
  }

  const int rq = (lane >> 4) * 4;
#pragma unroll
  for (int mi = 0; mi < 2; ++mi) {
#pragma unroll
    for (int ni = 0; ni < 2; ++ni) {
      const int ng = n0 + ni * 16 + m_lane;
      const float bias = (blockIdx.y == 0) ? bh[ng] : 0.0f;
#pragma unroll
      for (int r = 0; r < 4; ++r) {
        const int mg = w * 32 + mi * 16 + rq + r;
        atomicAdd(&Hf[(size_t)mg * HID + ng], acc[mi][ni][r] + bias);
      }
    }
  }
}

// cvt: Hf fp32 [128,4096] -> Hbf bf16 bits
__global__ __launch_bounds__(256) void cvt_kernel(
    const float* __restrict__ src, unsigned short* __restrict__ dst) {
  const int idx = blockIdx.x * 256 + threadIdx.x;
  float4 a = ((const float4*)src)[idx * 2];
  float4 b = ((const float4*)src)[idx * 2 + 1];
  U16x8 pk;
  pk.us[0] = f2bf(a.x); pk.us[1] = f2bf(a.y); pk.us[2] = f2bf(a.z); pk.us[3] = f2bf(a.w);
  pk.us[4] = f2bf(b.x); pk.us[5] = f2bf(b.y); pk.us[6] = f2bf(b.z); pk.us[7] = f2bf(b.w);
  ((uint4*)dst)[idx] = pk.v;
}

// GEMM2: emb[128,512] += hidden(bf16) @ W_e^T (+ b_e in split 0), fp32 atomics.
// grid (32 n-tiles, 8 k-splits), 256 thr. BM=128 BN=16 BK=64, 8 K-steps.
__global__ __launch_bounds__(256, 2) void gemm2_kernel(
    const unsigned short* __restrict__ Hbf, const float* __restrict__ We,
    const float* __restrict__ be, float* __restrict__ emb) {
  const int n0    = blockIdx.x * 16;
  const int kbase = blockIdx.y * 512;

  __shared__ __align__(16) unsigned short As[128 * 64];
  __shared__ __align__(16) unsigned short Ws[16 * 64];

  const int t = threadIdx.x, w = t >> 6, lane = t & 63;
  const int m_lane = lane & 15, kq = lane >> 4;
  f32x4 acc[2] = {};

  const int wr = t >> 4, wc = (t & 15) * 4;
  const float* Wg = We + (size_t)(n0 + wr) * HID + kbase + wc;
  float4 wv = ((const float4*)Wg)[0];
  Wg += 64;

  const int rowA = lane >> 3;
  const int gA   = (lane & 7) ^ rowA;

  for (int kt = 0; kt < 8; ++kt) {
    __syncthreads();
#pragma unroll
    for (int i = 0; i < 4; ++i) {
      const int m = i * 32 + w * 8 + rowA;
      const unsigned short* src = Hbf + (size_t)m * HID + kbase + kt * 64 + gA * 8;
      glds16(src, &As[(i * 256 + w * 64) * 8]);
    }
    {
      U16x4 pk;
      pk.us[0] = f2bf(wv.x); pk.us[1] = f2bf(wv.y); pk.us[2] = f2bf(wv.z); pk.us[3] = f2bf(wv.w);
      const int G = (t & 15) >> 1;
      *(uint2*)&Ws[wr * 64 + ((G ^ (wr & 7)) * 8) + (t & 1) * 4] = pk.v;
    }
    if (kt < 7) { wv = ((const float4*)Wg)[0]; Wg += 64; }
    __syncthreads();

#pragma unroll
    for (int ks = 0; ks < 2; ++ks) {
      const int Gk = ks * 4 + kq;
      const int m0 = w * 32 + m_lane, m1 = m0 + 16;
      bf16x8 a0 = *(const bf16x8*)&As[m0 * 64 + ((Gk ^ (m0 & 7)) * 8)];
      bf16x8 a1 = *(const bf16x8*)&As[m1 * 64 + ((Gk ^ (m1 & 7)) * 8)];
      bf16x8 b0 = *(const bf16x8*)&Ws[m_lane * 64 + ((Gk ^ (m_lane & 7)) * 8)];
      acc[0] = __builtin_amdgcn_mfma_f32_16x16x32_bf16(a0, b0, acc[0], 0, 0, 0);
      acc[1] = __builtin_amdgcn_mfma_f32_16x16x32_bf16(a1, b0, acc[1], 0, 0, 0);
    }
  }

  const int rq = (lane >> 4) * 4;
  const int ng = n0 + m_lane;
  const float bias = (blockIdx.y == 0) ? be[ng] : 0.0f;
#pragma unroll
  for (int mi = 0; mi < 2; ++mi) {
#pragma unroll
    for (int r = 0; r < 4; ++r) {
      const int mg = w * 32 + mi * 16 + rq + r;
      atomicAdd(&emb[mg * EMB + ng], acc[mi][r] + bias);
    }
  }
}

// Scores, e-stationary. Blocks 0..1023: 16 b x 16 negatives. 1024..1031: positives.
// Thread: tb = t>>4 (b row), s = t&15 (32-elem d-slice held in registers).
// LDS n-tile layout: row j at j*576 floats; d-slice s at s*36 (32 data + 4 pad,
// 16B-aligned, banks (4s+4i)%32 spread).
__global__ __launch_bounds__(256, 2) void score_kernel(
    const float* __restrict__ emb, const float* __restrict__ n_lfs,
    const float* __restrict__ p_lfs, float* __restrict__ out) {
  const int bx = blockIdx.x;
  const int t = threadIdx.x;
  const int s = t & 15, tb = t >> 4;

  if (bx < 1024) {
    const int nc = bx >> 3, bt = bx & 7;
    const int n0 = nc * 16, b0 = bt * 16;
    __shared__ __align__(16) float nl[16 * 576];
#pragma unroll
    for (int i = 0; i < 8; ++i) {
      const int f = t + i * 256;
      const int r = f >> 7, o4 = f & 127;
      float4 v = *(const float4*)(n_lfs + (size_t)(n0 + r) * EMB + o4 * 4);
      *(float4*)&nl[r * 576 + (o4 >> 3) * 36 + (o4 & 7) * 4] = v;
    }
    const float* eb = emb + (size_t)(b0 + tb) * EMB + s * 32;
    float4 ev[8];
#pragma unroll
    for (int i = 0; i < 8; ++i) ev[i] = *(const float4*)(eb + i * 4);
    __syncthreads();

    for (int j = 0; j < 16; ++j) {
      const float* nr = &nl[j * 576 + s * 36];
      float a0 = 0.f, a1 = 0.f, a2 = 0.f, a3 = 0.f;
#pragma unroll
      for (int i = 0; i < 8; ++i) {
        float4 nv = *(const float4*)(nr + i * 4);
        float d0 = fmaxf(nv.x - ev[i].x, 0.f);
        float d1 = fmaxf(nv.y - ev[i].y, 0.f);
        float d2 = fmaxf(nv.z - ev[i].z, 0.f);
        float d3 = fmaxf(nv.w - ev[i].w, 0.f);
        a0 = fmaf(d0, d0, a0); a1 = fmaf(d1, d1, a1);
        a2 = fmaf(d2, d2, a2); a3 = fmaf(d3, d3, a3);
      }
      float ss = (a0 + a1) + (a2 + a3);
      ss += __shfl_xor(ss, 1);
      ss += __shfl_xor(ss, 2);
      ss += __shfl_xor(ss, 4);
      ss += __shfl_xor(ss, 8);
      if (s == 0) out[(size_t)(b0 + tb) * OUTN + 1 + n0 + j] = -sqrtf(ss);
    }
  } else {
    const int b = (bx - 1024) * 16 + tb;
    const float* eb = emb + (size_t)b * EMB + s * 32;
    const float* pb = p_lfs + (size_t)b * EMB + s * 32;
    float a0 = 0.f, a1 = 0.f, a2 = 0.f, a3 = 0.f;
#pragma unroll
    for (int i = 0; i < 8; ++i) {
      float4 pv = *(const float4*)(pb + i * 4);
      float4 ev = *(const float4*)(eb + i * 4);
      float d0 = fmaxf(pv.x - ev.x, 0.f);
      float d1 = fmaxf(pv.y - ev.y, 0.f);
      float d2 = fmaxf(pv.z - ev.z, 0.f);
      float d3 = fmaxf(pv.w - ev.w, 0.f);
      a0 = fmaf(d0, d0, a0); a1 = fmaf(d1, d1, a1);
      a2 = fmaf(d2, d2, a2); a3 = fmaf(d3, d3, a3);
    }
    float ss = (a0 + a1) + (a2 + a3);
    ss += __shfl_xor(ss, 1);
    ss += __shfl_xor(ss, 2);
    ss += __shfl_xor(ss, 4);
    ss += __shfl_xor(ss, 8);
    if (s == 0) out[(size_t)b * OUTN] = -sqrtf(ss);
  }
}

extern "C" void kernel_launch(void* const* d_in, const int* in_sizes, int n_in,
                              void* d_out, int out_size, void* d_ws, size_t ws_size,
                              hipStream_t stream) {
  const float* vfs   = (const float*)d_in[0];
  const float* p_lfs = (const float*)d_in[1];
  const float* n_lfs = (const float*)d_in[2];
  const float* W_h   = (const float*)d_in[3];
  const float* b_h   = (const float*)d_in[4];
  const float* W_e   = (const float*)d_in[5];
  const float* b_e   = (const float*)d_in[6];
  float* out = (float*)d_out;

  // ws layout (4.25 MB): [Hf 2MB][emb 256KB][Abf 1MB][Hbf 1MB]
  char* ws = (char*)d_ws;
  float*          Hf  = (float*)ws;
  float*          emb = (float*)(ws + (2u << 20));
  unsigned short* Abf = (unsigned short*)(ws + (2u << 20) + (256u << 10));
  unsigned short* Hbf = (unsigned short*)(ws + (3u << 20) + (256u << 10));

  hipMemsetAsync(Hf, 0, (2u << 20) + (256u << 10), stream);   // Hf + emb
  prep_kernel<<<256, 256, 0, stream>>>(vfs, Abf);
  gemm1_kernel<<<dim3(HID / 32, 4), 256, 0, stream>>>(Abf, W_h, b_h, Hf);
  cvt_kernel<<<256, 256, 0, stream>>>(Hf, Hbf);
  gemm2_kernel<<<dim3(EMB / 16, 8), 256, 0, stream>>>(Hbf, W_e, b_e, emb);
  score_kernel<<<1032, 256, 0, stream>>>(emb, n_lfs, p_lfs, out);
}